// Round 6
// baseline (436.187 us; speedup 1.0000x reference)
//
#include <hip/hip_runtime.h>
#include <hip/hip_bf16.h>
#include <math.h>

// B=64, C=16, F=2048, J=25 ; EMBED=64, CLASSES=5, NJ=12
// stats: s2=max, s3=q25(pos 511.75), s4=xs[1023], s5=q75(pos 1535.25),
//        s6=mean, s7=std(ddof=1), s8=max-min, s9=kurtosis
// stat1/W1/b1 path is dead code in the reference. features[...,24] unused.
//
// Round-11: DE-BUNDLE. Ledger shows r6 (round-0) stat=228us was never
// beaten; r9/r10 restructures regressed via 4B-aligned float4 staging
// (4 scalar loads each) + register squeeze. This kernel = EXACT r6
// structure + only the two independently-verified wins:
//  (a) DS->DPP cross-lane swap (r8, bit-exact in r8/r10): lm 1,2,4,8 on
//      VALU DPP (4 pipes/CU) instead of ds_swizzle (1 DS unit/CU);
//      lm=16 stays ds_swizzle, lm=32 (wave_sum only) stays ds_bpermute.
//      Removes ~450 of ~530 DS ops per array.
//  (b) r8's prep/logits tail (verified exact) instead of fuse_kernel.
// Fixed harness overhead (total - stat) ~= 195us across all rounds; stat
// is the only lever. Tripwires: VGPR ~52, WRITE ~0.8MB, FETCH ~103MB.

#define F_LEN 2048
#define JTOT 25
#define STATS_PER_BC 192 // 16 s * 12 j
#define LP 2056          // LDS words per j-region (2048 + 8 so stride%32==8)

// Word swizzle: rotate each 32-word row by 4*(row&7) words, WRAPPED in-row.
__device__ __forceinline__ int swz(int i) {
  return (i & ~31) | ((i + ((i >> 5) << 2)) & 31);
}

// ds_swizzle with immediate xor pattern (BitMode: offset=(xor<<10)|0x1F).
template <int PAT>
__device__ __forceinline__ float ds_swz(float v) {
  return __int_as_float(
      __builtin_amdgcn_ds_swizzle(__float_as_int(v), PAT));
}

// DPP with compile-time ctrl/bank mask (row_mask always 0xF, bc=false).
template <int CTRL, int BANK>
__device__ __forceinline__ int upd_dpp(int old_, int src) {
  return __builtin_amdgcn_update_dpp(old_, src, CTRL, 0xF, BANK, false);
}

// Partner value at lane^lm. lm in {1,2,4,8}: pure VALU DPP (off the DS
// pipe). lm=16: ds_swizzle. lm=32: ds_bpermute with precomputed address.
// All patterns verified bit-exact on-harness in r8/r10.
__device__ __forceinline__ float xpartner(float v, const int lm,
                                          const int addr32) {
  const int vi = __float_as_int(v);
  switch (lm) {
    case 1:  // quad_perm [1,0,3,2]
      return __int_as_float(upd_dpp<0xB1, 0xF>(vi, vi));
    case 2:  // quad_perm [2,3,0,1]
      return __int_as_float(upd_dpp<0x4E, 0xF>(vi, vi));
    case 4: {
      // banks 0,2 (lane bit2==0): row_shl:4 -> reads lane+4
      // banks 1,3 (lane bit2==1): row_shr:4 -> reads lane-4
      const int t1 = upd_dpp<0x104, 0x5>(vi, vi);
      const int t2 = upd_dpp<0x114, 0xA>(t1, vi);
      return __int_as_float(t2);
    }
    case 8:  // row_ror:8 == xor8 within 16-row (symmetric, convention-proof)
      return __int_as_float(upd_dpp<0x128, 0xF>(vi, vi));
    case 16:
      return ds_swz<0x401F>(v);
    default:
      return __int_as_float(
          __builtin_amdgcn_ds_bpermute(addr32, vi));
  }
}

// full 64-lane sum via xpartner butterfly (only 2 DS ops).
__device__ __forceinline__ float wave_sum(float v, int addr32) {
  v += xpartner(v, 1, addr32);
  v += xpartner(v, 2, addr32);
  v += xpartner(v, 4, addr32);
  v += xpartner(v, 8, addr32);
  v += xpartner(v, 16, addr32);
  v += xpartner(v, 32, addr32);
  return v;
}

__global__ __launch_bounds__(256) void stat_kernel(
    const float* __restrict__ Fp, float* __restrict__ stat2) {
  __shared__ float lds[4 * LP]; // 32,896 B
  const int g = blockIdx.x;     // 0..6143
  const int xcd = g & 7;
  const int mm = g >> 3;
  const int bc = xcd * 128 + mm / 6;
  const int grp = mm % 6;
  const int t = threadIdx.x;
  const int w = t >> 6;
  const int lane = t & 63;
  const int addr32 = ((lane ^ 32) << 2);
  const int j0 = grp * 4;       // block stages j0..j0+3; wave w sorts j0+w
  float* wlds = lds + w * LP;

  // ---- phase 1: cooperative staging, [f][jj] -> LDS swizzled (r6) ----
  {
    const float* bbase = Fp + (size_t)bc * F_LEN * JTOT + j0;
    const int f0 = t >> 2, jj = t & 3;
    float* ldst = lds + jj * LP;
#pragma unroll
    for (int it = 0; it < 32; ++it) {
      const int f = it * 64 + f0;
      ldst[swz(f)] = bbase[(size_t)f * JTOT + jj];
    }
  }
  __syncthreads();

  // ---- phase 2: wave w reads its array as 8 conflict-free float4s ----
  float x[32];
  {
    const float4* src4 = (const float4*)wlds;
#pragma unroll
    for (int q = 0; q < 8; ++q) {
      float4 v = src4[lane * 8 + ((lane + q) & 7)];
      x[4 * q] = v.x; x[4 * q + 1] = v.y;
      x[4 * q + 2] = v.z; x[4 * q + 3] = v.w;
    }
  }

  // ---- moments (two-pass central) ----
  float sum = 0.f;
#pragma unroll
  for (int e = 0; e < 32; ++e) sum += x[e];
  sum = wave_sum(sum, addr32);
  const float m = sum * (1.0f / 2048.0f);

  float c2 = 0.f, c4 = 0.f;
#pragma unroll
  for (int e = 0; e < 32; ++e) {
    float d = x[e] - m;
    float dd = d * d;
    c2 += dd;
    c4 += dd * dd;
  }
  c2 = wave_sum(c2, addr32);
  c4 = wave_sum(c4, addr32);
  const float var = c2 * (1.0f / 2047.0f);  // ddof=1
  const float sd = sqrtf(var);
  const float kurt = (c4 * (1.0f / 2048.0f)) / (var * var) - 3.0f;

  // ---- bitonic stages 1..4: in-register, direction by e (compile-time) ----
#pragma unroll
  for (int kp = 1; kp <= 4; ++kp) {
    const int k = 1 << kp;
#pragma unroll
    for (int jp = kp - 1; jp >= 0; --jp) {
      const int st = 1 << jp;
#pragma unroll
      for (int e = 0; e < 32; ++e) {
        if ((e & st) == 0) {
          const bool up = ((e & k) == 0);
          float a = x[e], b = x[e + st];
          float lo2 = fminf(a, b), hi2 = fmaxf(a, b);
          x[e] = up ? lo2 : hi2;
          x[e + st] = up ? hi2 : lo2;
        }
      }
    }
  }

  // ---- stages 5..10: running sign-state Fst = direction ^ role ----
  unsigned Fst = 0u;
#pragma unroll
  for (int kp = 5; kp <= 10; ++kp) {
    const unsigned d = ((lane >> (kp - 5)) & 1) ? 0x80000000u : 0u;
#pragma unroll
    for (int jp = kp - 1; jp >= 5; --jp) {
      const int lm = 1 << (jp - 5);  // 1,2,4,8,16 — never crosses half-wave
      const unsigned r = ((lane >> (jp - 5)) & 1) ? 0x80000000u : 0u;
      const unsigned tgt = d ^ r;
      const unsigned fl = tgt ^ Fst;
      Fst = tgt;
#pragma unroll
      for (int e = 0; e < 32; ++e)
        x[e] = __uint_as_float(__float_as_uint(x[e]) ^ fl);
#pragma unroll
      for (int e = 0; e < 32; ++e) {
        float o = xpartner(x[e], lm, addr32);
        x[e] = fminf(x[e], -o); // uniform: keeps min (role-0) / -max (role-1)
      }
    }
    {
      const unsigned fl = d ^ Fst;
      Fst = d;
#pragma unroll
      for (int e = 0; e < 32; ++e)
        x[e] = __uint_as_float(__float_as_uint(x[e]) ^ fl);
    }
#pragma unroll
    for (int jp = (kp - 1 < 4 ? kp - 1 : 4); jp >= 0; --jp) {
      const int st = 1 << jp;
#pragma unroll
      for (int e = 0; e < 32; ++e) {
        if ((e & st) == 0) {
          float a = x[e], b = x[e + st];
          x[e] = fminf(a, b);
          x[e + st] = fmaxf(a, b);
        }
      }
    }
  }
#pragma unroll
  for (int e = 0; e < 32; ++e)
    x[e] = __uint_as_float(__float_as_uint(x[e]) ^ Fst);

  // ---- dump to LDS (region w now wave-private): [0..1023] asc,
  //      [1024..2047] desc, same wrapped swizzle ----
  {
    float4* dst4 = (float4*)wlds;
#pragma unroll
    for (int q = 0; q < 8; ++q) {
      int wq = 8 * lane + ((q + lane) & 7);
      dst4[wq] = make_float4(x[4 * q], x[4 * q + 1], x[4 * q + 2], x[4 * q + 3]);
    }
  }

  // ---- merge-path selection: lane i in 0..4 finds rank k_i ----
  const int kk = (lane == 0) ? 511
               : (lane == 1) ? 512
               : (lane == 2) ? 1023
               : (lane == 3) ? 1535 : 1536;
  const int mtot = kk + 1;
  int lo = mtot - 1024; if (lo < 0) lo = 0;
  int hi = (mtot < 1024) ? mtot : 1024;
  for (int it = 0; it < 11; ++it) {
    const bool act = lo < hi;
    const int s = (lo + hi) >> 1;
    const int sa = (s < 1023) ? s : 1023;
    float Av = wlds[swz(sa)];
    Av = (s < 1024) ? Av : INFINITY;
    int bidx = mtot - s - 1;
    bidx = bidx < 0 ? 0 : (bidx > 1023 ? 1023 : bidx);
    const float Bv = wlds[swz(2047 - bidx)];
    const bool gg = act && (Bv > Av);
    if (gg) lo = s + 1;
    else if (act) hi = s;
  }
  float val;
  {
    const int s = lo;
    const int ia = (s - 1 < 0) ? 0 : s - 1;
    const float fa = wlds[swz(ia)];
    const float fromA = (s > 0) ? fa : -INFINITY;
    const int bi = mtot - s - 1;
    const int ib = (bi < 0) ? 0 : bi;
    const float fb = wlds[swz(2047 - ib)];
    const float fromB = (bi >= 0) ? fb : -INFINITY;
    val = fmaxf(fromA, fromB);
  }

  const float a511  = __shfl(val, 0, 64);
  const float a512  = __shfl(val, 1, 64);
  const float amed  = __shfl(val, 2, 64);
  const float a1535 = __shfl(val, 3, 64);
  const float a1536 = __shfl(val, 4, 64);

  if (lane == 0) {
    const float mn = fminf(wlds[swz(0)], wlds[swz(2047)]);
    const float mx = fmaxf(wlds[swz(1023)], wlds[swz(1024)]);
    const float q25 = 0.25f * a511 + 0.75f * a512;    // pos = 511.75
    const float q75 = 0.75f * a1535 + 0.25f * a1536;  // pos = 1535.25
    const int j = j0 + w;
    const int jj = (j < 12) ? j : j - 12;
    const int sb = (j < 12) ? 0 : 8;
    float st8[8] = {mx, q25, amed, q75, m, sd, mx - mn, kurt};
    float* o = stat2 + (bc * 16 + sb) * 12 + jj;
#pragma unroll
    for (int s2 = 0; s2 < 8; ++s2) o[s2 * 12] = st8[s2];
  }
}

// ---------------------------------------------------------------------------
// prep: M[k,c,s,j] = sum_e Wl[k,e*16+s] * W2[e,c,j]   (5*16*16*12 = 15360)
//       C[k] = bl[k] + sum_e b2[e] * sum_s Wl[k,e*16+s]
// logits[b,k] = sum_i M[k,i] * stat2[b,i] + C[k],  i = c*192 + s*12 + j
// ---------------------------------------------------------------------------
__global__ __launch_bounds__(256) void prep_kernel(
    const float* __restrict__ W2, const float* __restrict__ b2,
    const float* __restrict__ Wl, const float* __restrict__ bl,
    float* __restrict__ M, float* __restrict__ C) {
  const int g = blockIdx.x;
  const int t = threadIdx.x;
  if (g < 60) {
    const int id = g * 256 + t; // k*3072 + c*192 + s*12 + j
    const int k = id / 3072;
    const int r = id % 3072;
    const int c = r / 192;
    const int s = (r % 192) / 12;
    const int j = r % 12;
    const float* wl = Wl + k * 1024 + s;
    const float* w2 = W2 + c * 12 + j;
    float acc = 0.f;
#pragma unroll 8
    for (int e = 0; e < 64; ++e) acc += wl[e * 16] * w2[e * 192];
    M[id] = acc;
  } else if (t < 64) { // one wave computes C[0..4]
    const int e = t;
    const int addr32 = ((e ^ 32) << 2);
    for (int k = 0; k < 5; ++k) {
      const float* wl = Wl + k * 1024 + e * 16;
      float rs = 0.f;
#pragma unroll
      for (int s = 0; s < 16; ++s) rs += wl[s];
      float v = wave_sum(rs * b2[e], addr32);
      if (e == 0) C[k] = v + bl[k];
    }
  }
}

__global__ __launch_bounds__(256) void logits_kernel(
    const float* __restrict__ stat2, const float* __restrict__ M,
    const float* __restrict__ C, float* __restrict__ out) {
  __shared__ float s_red[20];
  const int b = blockIdx.x;
  const int t = threadIdx.x;
  const int lane = t & 63;
  const int w = t >> 6;
  const int addr32 = ((lane ^ 32) << 2);

  float acc[5] = {0.f, 0.f, 0.f, 0.f, 0.f};
#pragma unroll
  for (int ii = 0; ii < 12; ++ii) {
    const int i = ii * 256 + t;
    const float s = stat2[b * 3072 + i];
#pragma unroll
    for (int k = 0; k < 5; ++k) acc[k] += s * M[k * 3072 + i];
  }
#pragma unroll
  for (int k = 0; k < 5; ++k) acc[k] = wave_sum(acc[k], addr32);
  if (lane == 0) {
#pragma unroll
    for (int k = 0; k < 5; ++k) s_red[w * 5 + k] = acc[k];
  }
  __syncthreads();
  if (t < 5)
    out[b * 5 + t] =
        s_red[t] + s_red[5 + t] + s_red[10 + t] + s_red[15 + t] + C[t];
}

extern "C" void kernel_launch(void* const* d_in, const int* in_sizes, int n_in,
                              void* d_out, int out_size, void* d_ws,
                              size_t ws_size, hipStream_t stream) {
  const float* Fp = (const float*)d_in[0];
  // d_in[1] = W1, d_in[2] = b1 -> dead code in reference, unused.
  const float* W2 = (const float*)d_in[3];
  const float* b2 = (const float*)d_in[4];
  const float* Wl = (const float*)d_in[5];
  const float* bl = (const float*)d_in[6];
  float* out = (float*)d_out;

  float* stat2 = (float*)d_ws; // 1024*192 floats = 768 KB
  float* M = stat2 + 196608;   // 15360 floats
  float* C = M + 15360;        // 5 floats

  prep_kernel<<<61, 256, 0, stream>>>(W2, b2, Wl, bl, M, C);
  stat_kernel<<<6144, 256, 0, stream>>>(Fp, stat2);
  logits_kernel<<<64, 256, 0, stream>>>(stat2, M, C, out);
}

// Round 7
// 382.565 us; speedup vs baseline: 1.1402x; 1.1402x over previous
//
#include <hip/hip_runtime.h>
#include <hip/hip_bf16.h>
#include <math.h>

// B=64, C=16, F=2048, J=25 ; EMBED=64, CLASSES=5, NJ=12
// stats: s2=max, s3=q25(pos 511.75), s4=xs[1023], s5=q75(pos 1535.25),
//        s6=mean, s7=std(ddof=1), s8=max-min, s9=kurtosis
// stat1/W1/b1 path is dead code in the reference. features[...,24] unused.
//
// Round-12: inline-asm cross-lane substages (ILP by decree).
//  Cycle model (closes on r6/r11 data): cross-lane substage element =
//  dependent chain xor->dpp->min at ~4-6cy RAW latency; compiler pins
//  4 spare VGPRs and overlaps ~2 chains -> ~6.5 cy/inst on the 2048-inst
//  cross-lane block = 13K of the 24K busy cycles/wave. In-reg min/max
//  substages are depth-1 (2cy/inst, fine). Fix: 8-element-batched asm
//  blocks (8 xor, 8 v_mov_b32_dpp, 8 v_min -src) — order + 8 earlyclobber
//  temps forced, DPP hazard (2 waits) satisfied by >=8-inst separation.
//  DPP controls identical to the bit-exact r8/r10/r11 builtins.
//  Prediction: stat 240 -> 110-160us; >=200 refutes -> pivot to
//  count-bisect selection. Tripwire: WRITE ~0.78MB (no spill).

#define F_LEN 2048
#define JTOT 25
#define STATS_PER_BC 192 // 16 s * 12 j
#define LP 2056          // LDS words per j-region (2048 + 8 so stride%32==8)

// Word swizzle: rotate each 32-word row by 4*(row&7) words, WRAPPED in-row.
__device__ __forceinline__ int swz(int i) {
  return (i & ~31) | ((i + ((i >> 5) << 2)) & 31);
}

// ds_swizzle with immediate xor pattern (BitMode: offset=(xor<<10)|0x1F).
template <int PAT>
__device__ __forceinline__ float ds_swz(float v) {
  return __int_as_float(
      __builtin_amdgcn_ds_swizzle(__float_as_int(v), PAT));
}

// DPP with compile-time ctrl/bank mask (row_mask always 0xF, bc=false).
template <int CTRL, int BANK>
__device__ __forceinline__ int upd_dpp(int old_, int src) {
  return __builtin_amdgcn_update_dpp(old_, src, CTRL, 0xF, BANK, false);
}

// Builtin partner (used only in wave_sum / lm=16): verified bit-exact.
__device__ __forceinline__ float xpartner(float v, const int lm,
                                          const int addr32) {
  const int vi = __float_as_int(v);
  switch (lm) {
    case 1:  return __int_as_float(upd_dpp<0xB1, 0xF>(vi, vi));
    case 2:  return __int_as_float(upd_dpp<0x4E, 0xF>(vi, vi));
    case 4: {
      const int t1 = upd_dpp<0x104, 0x5>(vi, vi);
      const int t2 = upd_dpp<0x114, 0xA>(t1, vi);
      return __int_as_float(t2);
    }
    case 8:  return __int_as_float(upd_dpp<0x128, 0xF>(vi, vi));
    case 16: return ds_swz<0x401F>(v);
    default:
      return __int_as_float(
          __builtin_amdgcn_ds_bpermute(addr32, vi));
  }
}

// full 64-lane sum via xpartner butterfly.
__device__ __forceinline__ float wave_sum(float v, int addr32) {
  v += xpartner(v, 1, addr32);
  v += xpartner(v, 2, addr32);
  v += xpartner(v, 4, addr32);
  v += xpartner(v, 8, addr32);
  v += xpartner(v, 16, addr32);
  v += xpartner(v, 32, addr32);
  return v;
}

// ---- 8-element-batched cross-lane substage: x ^= fl; t = dpp(x);
//      x = min(x, -t). Single-DPP controls (lm = 1, 2, 8). ----
#define XSUB8(CTRL, a0, a1, a2, a3, a4, a5, a6, a7, FL)                       \
  do {                                                                        \
    float t0, t1, t2, t3, t4, t5, t6, t7;                                     \
    asm volatile(                                                             \
        "v_xor_b32 %0, %16, %0\n\t"                                           \
        "v_xor_b32 %1, %16, %1\n\t"                                           \
        "v_xor_b32 %2, %16, %2\n\t"                                           \
        "v_xor_b32 %3, %16, %3\n\t"                                           \
        "v_xor_b32 %4, %16, %4\n\t"                                           \
        "v_xor_b32 %5, %16, %5\n\t"                                           \
        "v_xor_b32 %6, %16, %6\n\t"                                           \
        "v_xor_b32 %7, %16, %7\n\t"                                           \
        "v_mov_b32_dpp %8, %0 " CTRL "\n\t"                                   \
        "v_mov_b32_dpp %9, %1 " CTRL "\n\t"                                   \
        "v_mov_b32_dpp %10, %2 " CTRL "\n\t"                                  \
        "v_mov_b32_dpp %11, %3 " CTRL "\n\t"                                  \
        "v_mov_b32_dpp %12, %4 " CTRL "\n\t"                                  \
        "v_mov_b32_dpp %13, %5 " CTRL "\n\t"                                  \
        "v_mov_b32_dpp %14, %6 " CTRL "\n\t"                                  \
        "v_mov_b32_dpp %15, %7 " CTRL "\n\t"                                  \
        "v_min_f32 %0, %0, -%8\n\t"                                           \
        "v_min_f32 %1, %1, -%9\n\t"                                           \
        "v_min_f32 %2, %2, -%10\n\t"                                          \
        "v_min_f32 %3, %3, -%11\n\t"                                          \
        "v_min_f32 %4, %4, -%12\n\t"                                          \
        "v_min_f32 %5, %5, -%13\n\t"                                          \
        "v_min_f32 %6, %6, -%14\n\t"                                          \
        "v_min_f32 %7, %7, -%15\n\t"                                          \
        : "+v"(a0), "+v"(a1), "+v"(a2), "+v"(a3), "+v"(a4), "+v"(a5),         \
          "+v"(a6), "+v"(a7), "=&v"(t0), "=&v"(t1), "=&v"(t2), "=&v"(t3),     \
          "=&v"(t4), "=&v"(t5), "=&v"(t6), "=&v"(t7)                          \
        : "v"(FL));                                                           \
  } while (0)

// lm = 4: xor-4 via bank-masked shl/shr pair into the same temp
// (banks 0,2 <- row_shl:4 ; banks 1,3 <- row_shr:4), exactly the verified
// builtin sequence (ctrl 0x104/bank 0x5 then 0x114/bank 0xA).
#define XSUB8_X4(a0, a1, a2, a3, a4, a5, a6, a7, FL)                          \
  do {                                                                        \
    float t0, t1, t2, t3, t4, t5, t6, t7;                                     \
    asm volatile(                                                             \
        "v_xor_b32 %0, %16, %0\n\t"                                           \
        "v_xor_b32 %1, %16, %1\n\t"                                           \
        "v_xor_b32 %2, %16, %2\n\t"                                           \
        "v_xor_b32 %3, %16, %3\n\t"                                           \
        "v_xor_b32 %4, %16, %4\n\t"                                           \
        "v_xor_b32 %5, %16, %5\n\t"                                           \
        "v_xor_b32 %6, %16, %6\n\t"                                           \
        "v_xor_b32 %7, %16, %7\n\t"                                           \
        "v_mov_b32_dpp %8, %0 row_shl:4 row_mask:0xf bank_mask:0x5\n\t"       \
        "v_mov_b32_dpp %9, %1 row_shl:4 row_mask:0xf bank_mask:0x5\n\t"       \
        "v_mov_b32_dpp %10, %2 row_shl:4 row_mask:0xf bank_mask:0x5\n\t"      \
        "v_mov_b32_dpp %11, %3 row_shl:4 row_mask:0xf bank_mask:0x5\n\t"      \
        "v_mov_b32_dpp %12, %4 row_shl:4 row_mask:0xf bank_mask:0x5\n\t"      \
        "v_mov_b32_dpp %13, %5 row_shl:4 row_mask:0xf bank_mask:0x5\n\t"      \
        "v_mov_b32_dpp %14, %6 row_shl:4 row_mask:0xf bank_mask:0x5\n\t"      \
        "v_mov_b32_dpp %15, %7 row_shl:4 row_mask:0xf bank_mask:0x5\n\t"      \
        "v_mov_b32_dpp %8, %0 row_shr:4 row_mask:0xf bank_mask:0xa\n\t"       \
        "v_mov_b32_dpp %9, %1 row_shr:4 row_mask:0xf bank_mask:0xa\n\t"       \
        "v_mov_b32_dpp %10, %2 row_shr:4 row_mask:0xf bank_mask:0xa\n\t"      \
        "v_mov_b32_dpp %11, %3 row_shr:4 row_mask:0xf bank_mask:0xa\n\t"      \
        "v_mov_b32_dpp %12, %4 row_shr:4 row_mask:0xf bank_mask:0xa\n\t"      \
        "v_mov_b32_dpp %13, %5 row_shr:4 row_mask:0xf bank_mask:0xa\n\t"      \
        "v_mov_b32_dpp %14, %6 row_shr:4 row_mask:0xf bank_mask:0xa\n\t"      \
        "v_mov_b32_dpp %15, %7 row_shr:4 row_mask:0xf bank_mask:0xa\n\t"      \
        "v_min_f32 %0, %0, -%8\n\t"                                           \
        "v_min_f32 %1, %1, -%9\n\t"                                           \
        "v_min_f32 %2, %2, -%10\n\t"                                          \
        "v_min_f32 %3, %3, -%11\n\t"                                          \
        "v_min_f32 %4, %4, -%12\n\t"                                          \
        "v_min_f32 %5, %5, -%13\n\t"                                          \
        "v_min_f32 %6, %6, -%14\n\t"                                          \
        "v_min_f32 %7, %7, -%15\n\t"                                          \
        : "+v"(a0), "+v"(a1), "+v"(a2), "+v"(a3), "+v"(a4), "+v"(a5),         \
          "+v"(a6), "+v"(a7), "=&v"(t0), "=&v"(t1), "=&v"(t2), "=&v"(t3),     \
          "=&v"(t4), "=&v"(t5), "=&v"(t6), "=&v"(t7)                          \
        : "v"(FL));                                                           \
  } while (0)

#define QP1 "quad_perm:[1,0,3,2] row_mask:0xf bank_mask:0xf"
#define QP2 "quad_perm:[2,3,0,1] row_mask:0xf bank_mask:0xf"
#define ROR8 "row_ror:8 row_mask:0xf bank_mask:0xf"

#define XSUB32(M, CTRL, X, FL)                                                \
  do {                                                                        \
    M(CTRL, X[0], X[1], X[2], X[3], X[4], X[5], X[6], X[7], FL);              \
    M(CTRL, X[8], X[9], X[10], X[11], X[12], X[13], X[14], X[15], FL);        \
    M(CTRL, X[16], X[17], X[18], X[19], X[20], X[21], X[22], X[23], FL);      \
    M(CTRL, X[24], X[25], X[26], X[27], X[28], X[29], X[30], X[31], FL);      \
  } while (0)

#define XSUB32_X4(X, FL)                                                      \
  do {                                                                        \
    XSUB8_X4(X[0], X[1], X[2], X[3], X[4], X[5], X[6], X[7], FL);             \
    XSUB8_X4(X[8], X[9], X[10], X[11], X[12], X[13], X[14], X[15], FL);       \
    XSUB8_X4(X[16], X[17], X[18], X[19], X[20], X[21], X[22], X[23], FL);     \
    XSUB8_X4(X[24], X[25], X[26], X[27], X[28], X[29], X[30], X[31], FL);     \
  } while (0)

__global__ __launch_bounds__(256) void stat_kernel(
    const float* __restrict__ Fp, float* __restrict__ stat2) {
  __shared__ float lds[4 * LP]; // 32,896 B
  const int g = blockIdx.x;     // 0..6143
  const int xcd = g & 7;
  const int mm = g >> 3;
  const int bc = xcd * 128 + mm / 6;
  const int grp = mm % 6;
  const int t = threadIdx.x;
  const int w = t >> 6;
  const int lane = t & 63;
  const int addr32 = ((lane ^ 32) << 2);
  const int j0 = grp * 4;       // block stages j0..j0+3; wave w sorts j0+w
  float* wlds = lds + w * LP;

  // ---- phase 1: cooperative staging, [f][jj] -> LDS swizzled (r6) ----
  {
    const float* bbase = Fp + (size_t)bc * F_LEN * JTOT + j0;
    const int f0 = t >> 2, jj = t & 3;
    float* ldst = lds + jj * LP;
#pragma unroll
    for (int it = 0; it < 32; ++it) {
      const int f = it * 64 + f0;
      ldst[swz(f)] = bbase[(size_t)f * JTOT + jj];
    }
  }
  __syncthreads();

  // ---- phase 2: wave w reads its array as 8 conflict-free float4s ----
  float x[32];
  {
    const float4* src4 = (const float4*)wlds;
#pragma unroll
    for (int q = 0; q < 8; ++q) {
      float4 v = src4[lane * 8 + ((lane + q) & 7)];
      x[4 * q] = v.x; x[4 * q + 1] = v.y;
      x[4 * q + 2] = v.z; x[4 * q + 3] = v.w;
    }
  }

  // ---- moments (two-pass central) ----
  float sum = 0.f;
#pragma unroll
  for (int e = 0; e < 32; ++e) sum += x[e];
  sum = wave_sum(sum, addr32);
  const float m = sum * (1.0f / 2048.0f);

  float c2 = 0.f, c4 = 0.f;
#pragma unroll
  for (int e = 0; e < 32; ++e) {
    float d = x[e] - m;
    float dd = d * d;
    c2 += dd;
    c4 += dd * dd;
  }
  c2 = wave_sum(c2, addr32);
  c4 = wave_sum(c4, addr32);
  const float var = c2 * (1.0f / 2047.0f);  // ddof=1
  const float sd = sqrtf(var);
  const float kurt = (c4 * (1.0f / 2048.0f)) / (var * var) - 3.0f;

  // ---- bitonic stages 1..4: in-register, direction by e (compile-time) ----
#pragma unroll
  for (int kp = 1; kp <= 4; ++kp) {
    const int k = 1 << kp;
#pragma unroll
    for (int jp = kp - 1; jp >= 0; --jp) {
      const int st = 1 << jp;
#pragma unroll
      for (int e = 0; e < 32; ++e) {
        if ((e & st) == 0) {
          const bool up = ((e & k) == 0);
          float a = x[e], b = x[e + st];
          float lo2 = fminf(a, b), hi2 = fmaxf(a, b);
          x[e] = up ? lo2 : hi2;
          x[e + st] = up ? hi2 : lo2;
        }
      }
    }
  }

  // ---- stages 5..10: running sign-state Fst = direction ^ role ----
  unsigned Fst = 0u;
#pragma unroll
  for (int kp = 5; kp <= 10; ++kp) {
    const unsigned d = ((lane >> (kp - 5)) & 1) ? 0x80000000u : 0u;
#pragma unroll
    for (int jp = kp - 1; jp >= 5; --jp) {
      const int lm = 1 << (jp - 5);  // 1,2,4,8,16 — never crosses half-wave
      const unsigned r = ((lane >> (jp - 5)) & 1) ? 0x80000000u : 0u;
      const unsigned tgt = d ^ r;
      const unsigned fl = tgt ^ Fst;
      Fst = tgt;
      if (lm == 16) {
        // single substage: keep verified ds_swizzle path
#pragma unroll
        for (int e = 0; e < 32; ++e)
          x[e] = __uint_as_float(__float_as_uint(x[e]) ^ fl);
#pragma unroll
        for (int e = 0; e < 32; ++e) {
          float o = ds_swz<0x401F>(x[e]);
          x[e] = fminf(x[e], -o);
        }
      } else if (lm == 1) {
        XSUB32(XSUB8, QP1, x, fl);
      } else if (lm == 2) {
        XSUB32(XSUB8, QP2, x, fl);
      } else if (lm == 4) {
        XSUB32_X4(x, fl);
      } else { // lm == 8
        XSUB32(XSUB8, ROR8, x, fl);
      }
    }
    {
      const unsigned fl = d ^ Fst;
      Fst = d;
#pragma unroll
      for (int e = 0; e < 32; ++e)
        x[e] = __uint_as_float(__float_as_uint(x[e]) ^ fl);
    }
#pragma unroll
    for (int jp = (kp - 1 < 4 ? kp - 1 : 4); jp >= 0; --jp) {
      const int st = 1 << jp;
#pragma unroll
      for (int e = 0; e < 32; ++e) {
        if ((e & st) == 0) {
          float a = x[e], b = x[e + st];
          x[e] = fminf(a, b);
          x[e + st] = fmaxf(a, b);
        }
      }
    }
  }
#pragma unroll
  for (int e = 0; e < 32; ++e)
    x[e] = __uint_as_float(__float_as_uint(x[e]) ^ Fst);

  // ---- dump to LDS (region w now wave-private): [0..1023] asc,
  //      [1024..2047] desc, same wrapped swizzle ----
  {
    float4* dst4 = (float4*)wlds;
#pragma unroll
    for (int q = 0; q < 8; ++q) {
      int wq = 8 * lane + ((q + lane) & 7);
      dst4[wq] = make_float4(x[4 * q], x[4 * q + 1], x[4 * q + 2], x[4 * q + 3]);
    }
  }

  // ---- merge-path selection: lane i in 0..4 finds rank k_i ----
  const int kk = (lane == 0) ? 511
               : (lane == 1) ? 512
               : (lane == 2) ? 1023
               : (lane == 3) ? 1535 : 1536;
  const int mtot = kk + 1;
  int lo = mtot - 1024; if (lo < 0) lo = 0;
  int hi = (mtot < 1024) ? mtot : 1024;
  for (int it = 0; it < 11; ++it) {
    const bool act = lo < hi;
    const int s = (lo + hi) >> 1;
    const int sa = (s < 1023) ? s : 1023;
    float Av = wlds[swz(sa)];
    Av = (s < 1024) ? Av : INFINITY;
    int bidx = mtot - s - 1;
    bidx = bidx < 0 ? 0 : (bidx > 1023 ? 1023 : bidx);
    const float Bv = wlds[swz(2047 - bidx)];
    const bool gg = act && (Bv > Av);
    if (gg) lo = s + 1;
    else if (act) hi = s;
  }
  float val;
  {
    const int s = lo;
    const int ia = (s - 1 < 0) ? 0 : s - 1;
    const float fa = wlds[swz(ia)];
    const float fromA = (s > 0) ? fa : -INFINITY;
    const int bi = mtot - s - 1;
    const int ib = (bi < 0) ? 0 : bi;
    const float fb = wlds[swz(2047 - ib)];
    const float fromB = (bi >= 0) ? fb : -INFINITY;
    val = fmaxf(fromA, fromB);
  }

  const float a511  = __shfl(val, 0, 64);
  const float a512  = __shfl(val, 1, 64);
  const float amed  = __shfl(val, 2, 64);
  const float a1535 = __shfl(val, 3, 64);
  const float a1536 = __shfl(val, 4, 64);

  if (lane == 0) {
    const float mn = fminf(wlds[swz(0)], wlds[swz(2047)]);
    const float mx = fmaxf(wlds[swz(1023)], wlds[swz(1024)]);
    const float q25 = 0.25f * a511 + 0.75f * a512;    // pos = 511.75
    const float q75 = 0.75f * a1535 + 0.25f * a1536;  // pos = 1535.25
    const int j = j0 + w;
    const int jj = (j < 12) ? j : j - 12;
    const int sb = (j < 12) ? 0 : 8;
    float st8[8] = {mx, q25, amed, q75, m, sd, mx - mn, kurt};
    float* o = stat2 + (bc * 16 + sb) * 12 + jj;
#pragma unroll
    for (int s2 = 0; s2 < 8; ++s2) o[s2 * 12] = st8[s2];
  }
}

// ---------------------------------------------------------------------------
// prep: M[k,c,s,j] = sum_e Wl[k,e*16+s] * W2[e,c,j]   (5*16*16*12 = 15360)
//       C[k] = bl[k] + sum_e b2[e] * sum_s Wl[k,e*16+s]
// logits[b,k] = sum_i M[k,i] * stat2[b,i] + C[k],  i = c*192 + s*12 + j
// ---------------------------------------------------------------------------
__global__ __launch_bounds__(256) void prep_kernel(
    const float* __restrict__ W2, const float* __restrict__ b2,
    const float* __restrict__ Wl, const float* __restrict__ bl,
    float* __restrict__ M, float* __restrict__ C) {
  const int g = blockIdx.x;
  const int t = threadIdx.x;
  if (g < 60) {
    const int id = g * 256 + t; // k*3072 + c*192 + s*12 + j
    const int k = id / 3072;
    const int r = id % 3072;
    const int c = r / 192;
    const int s = (r % 192) / 12;
    const int j = r % 12;
    const float* wl = Wl + k * 1024 + s;
    const float* w2 = W2 + c * 12 + j;
    float acc = 0.f;
#pragma unroll 8
    for (int e = 0; e < 64; ++e) acc += wl[e * 16] * w2[e * 192];
    M[id] = acc;
  } else if (t < 64) { // one wave computes C[0..4]
    const int e = t;
    const int addr32 = ((e ^ 32) << 2);
    for (int k = 0; k < 5; ++k) {
      const float* wl = Wl + k * 1024 + e * 16;
      float rs = 0.f;
#pragma unroll
      for (int s = 0; s < 16; ++s) rs += wl[s];
      float v = wave_sum(rs * b2[e], addr32);
      if (e == 0) C[k] = v + bl[k];
    }
  }
}

__global__ __launch_bounds__(256) void logits_kernel(
    const float* __restrict__ stat2, const float* __restrict__ M,
    const float* __restrict__ C, float* __restrict__ out) {
  __shared__ float s_red[20];
  const int b = blockIdx.x;
  const int t = threadIdx.x;
  const int lane = t & 63;
  const int w = t >> 6;
  const int addr32 = ((lane ^ 32) << 2);

  float acc[5] = {0.f, 0.f, 0.f, 0.f, 0.f};
#pragma unroll
  for (int ii = 0; ii < 12; ++ii) {
    const int i = ii * 256 + t;
    const float s = stat2[b * 3072 + i];
#pragma unroll
    for (int k = 0; k < 5; ++k) acc[k] += s * M[k * 3072 + i];
  }
#pragma unroll
  for (int k = 0; k < 5; ++k) acc[k] = wave_sum(acc[k], addr32);
  if (lane == 0) {
#pragma unroll
    for (int k = 0; k < 5; ++k) s_red[w * 5 + k] = acc[k];
  }
  __syncthreads();
  if (t < 5)
    out[b * 5 + t] =
        s_red[t] + s_red[5 + t] + s_red[10 + t] + s_red[15 + t] + C[t];
}

extern "C" void kernel_launch(void* const* d_in, const int* in_sizes, int n_in,
                              void* d_out, int out_size, void* d_ws,
                              size_t ws_size, hipStream_t stream) {
  const float* Fp = (const float*)d_in[0];
  // d_in[1] = W1, d_in[2] = b1 -> dead code in reference, unused.
  const float* W2 = (const float*)d_in[3];
  const float* b2 = (const float*)d_in[4];
  const float* Wl = (const float*)d_in[5];
  const float* bl = (const float*)d_in[6];
  float* out = (float*)d_out;

  float* stat2 = (float*)d_ws; // 1024*192 floats = 768 KB
  float* M = stat2 + 196608;   // 15360 floats
  float* C = M + 15360;        // 5 floats

  prep_kernel<<<61, 256, 0, stream>>>(W2, b2, Wl, bl, M, C);
  stat_kernel<<<6144, 256, 0, stream>>>(Fp, stat2);
  logits_kernel<<<64, 256, 0, stream>>>(stat2, M, C, out);
}